// Round 3
// baseline (3113.286 us; speedup 1.0000x reference)
//
#include <hip/hip_runtime.h>
#include <hip/hip_bf16.h>
#include <stdint.h>

// B,S,H,I = 4,2048,4096,11008 ; M = B*S = 8192
static constexpr int Hd = 4096;
static constexpr int Id = 11008;
static constexpr int Md = 8192;

using short8 = __attribute__((ext_vector_type(8))) short;
using f32x4  = __attribute__((ext_vector_type(4))) float;

__device__ __forceinline__ unsigned short f2bf(float x) {
    union { float f; unsigned u; } v; v.f = x;
    unsigned r = v.u + 0x7FFF + ((v.u >> 16) & 1);   // RNE
    return (unsigned short)(r >> 16);
}

typedef const __attribute__((address_space(1))) unsigned int* as1_u32p;
typedef __attribute__((address_space(3))) unsigned int* as3_u32p;

__device__ __forceinline__ void gload16(const unsigned short* g, unsigned short* l) {
    __builtin_amdgcn_global_load_lds((as1_u32p)(const void*)g, (as3_u32p)(void*)l, 16, 0, 0);
}

// swizzled chunk offset (ushort index) within a [128 rows][64 cols] bf16 half-tile.
// chunk = 8 shorts (16B); 8 chunks per row; XOR row&7 into chunk-col.
#define AOFF(r, c) ((((r) * 8) + ((c) ^ ((r) & 7))) * 8)

#define LGKM0() do { asm volatile("s_waitcnt lgkmcnt(0)" ::: "memory"); \
                     __builtin_amdgcn_sched_barrier(0); } while (0)
#define VMCNT0() do { asm volatile("s_waitcnt vmcnt(0)" ::: "memory"); \
                      __builtin_amdgcn_sched_barrier(0); } while (0)
#define BARRIER() do { asm volatile("" ::: "memory"); __builtin_amdgcn_s_barrier(); \
                       asm volatile("" ::: "memory"); } while (0)

// stage one 128x64 half-tile of operand X into LDS (2 global_load_lds per thread)
#define STAGE(Xs, Xb, xR0, xR1, dd, h, kt) do {                                  \
    const size_t ho_ = (size_t)(h) * 128 * K + (size_t)(kt) * 64;                \
    gload16(Xb + xR0 + ho_, &Xs[dd][h][wave * 512]);                             \
    gload16(Xb + xR1 + ho_, &Xs[dd][h][4096 + wave * 512]);                      \
} while (0)

// ---------------------------------------------------------------------------
// fp32 -> bf16 bulk converter
// ---------------------------------------------------------------------------
__global__ __launch_bounds__(256) void k_cvt(const float* __restrict__ in,
                                             unsigned short* __restrict__ out, int n8) {
    int i = blockIdx.x * blockDim.x + threadIdx.x;
    const int stride = gridDim.x * blockDim.x;
    for (; i < n8; i += stride) {
        f32x4 a = *(const f32x4*)(in + (size_t)i * 8);
        f32x4 b = *(const f32x4*)(in + (size_t)i * 8 + 4);
        short8 v;
        v[0] = (short)f2bf(a[0]); v[1] = (short)f2bf(a[1]);
        v[2] = (short)f2bf(a[2]); v[3] = (short)f2bf(a[3]);
        v[4] = (short)f2bf(b[0]); v[5] = (short)f2bf(b[1]);
        v[6] = (short)f2bf(b[2]); v[7] = (short)f2bf(b[3]);
        *reinterpret_cast<short8*>(out + (size_t)i * 8) = v;
    }
}

// ---------------------------------------------------------------------------
// 256x256-tile, BK=64, 8-wave (2Mx4N), 4-phase pipelined GEMM: C = A (MxK) . B^T (NxK)
// MODE 0: Cb[row*ldC+col] = bf16(acc)                  (up proj)
// MODE 1: Cb[..] = bf16( silu(acc) * bf2f(Cb[..]) )    (gate proj, RMW SwiGLU)
// MODE 2: Cf[..] = acc                                 (down proj, fp32 out)
// ---------------------------------------------------------------------------
template<int MODE>
__global__ __launch_bounds__(512, 2) void gemm8p(
    const unsigned short* __restrict__ A, const unsigned short* __restrict__ B,
    unsigned short* __restrict__ Cb, float* __restrict__ Cf,
    const int K, const int ldC)
{
    __shared__ unsigned short As[2][2][8192];   // [dbuf][half][128*64]
    __shared__ unsigned short Bs[2][2][8192];   // 128 KiB total

    const int tid  = threadIdx.x;
    const int wave = tid >> 6;
    const int lane = tid & 63;
    const int wm   = wave >> 2;          // 0..1 -> C rows wm*128
    const int wn   = wave & 3;           // 0..3 -> C cols wn*64
    const int r16  = lane & 15;
    const int kg   = lane >> 4;          // 0..3

    const int nwg = gridDim.x;           // divisible by 8
    const int bid = blockIdx.x;
    const int swz = (bid & 7) * (nwg >> 3) + (bid >> 3);   // XCD swizzle (bijective)
    const int m0  = (swz & 31) * 256;    // M/256 = 32 tiles, m-fastest
    const int n0  = (swz >> 5) * 256;

    // staging coords: thread covers chunks {tid, 512+tid} of each half-tile
    const int i0 = tid,       r0 = i0 >> 3;
    const int i1 = 512 + tid, r1 = i1 >> 3;
    const int cc0 = (i0 & 7) ^ (r0 & 7);   // pre-swizzled source chunk-col
    const int cc1 = (i1 & 7) ^ (r1 & 7);
    const size_t aR0 = (size_t)(m0 + r0) * K + cc0 * 8;
    const size_t aR1 = (size_t)(m0 + r1) * K + cc1 * 8;
    const size_t bR0 = (size_t)(n0 + r0) * K + cc0 * 8;
    const size_t bR1 = (size_t)(n0 + r1) * K + cc1 * 8;

    f32x4 acc[8][4] = {};
    short8 af[4][2], b0f[2][2], b1f[2][2];

    // prologue: stage k-tile 0 fully into dbuf 0
    STAGE(As, A, aR0, aR1, 0, 0, 0);
    STAGE(Bs, B, bR0, bR1, 0, 0, 0);
    STAGE(As, A, aR0, aR1, 0, 1, 0);
    STAGE(Bs, B, bR0, bR1, 0, 1, 0);
    VMCNT0();
    BARRIER();

    const int NT = K >> 6;
    for (int kt = 0; kt < NT; ++kt) {
        const int d  = kt & 1;
        const int nd = d ^ 1;
        const bool more = (kt + 1) < NT;

        // ---------------- P1: quadrant (mi 0-3, ni 0-1) ----------------
        #pragma unroll
        for (int mi = 0; mi < 4; ++mi)
            #pragma unroll
            for (int kk = 0; kk < 2; ++kk)
                af[mi][kk] = *(const short8*)&As[d][wm][AOFF(mi * 16 + r16, kk * 4 + kg)];
        #pragma unroll
        for (int ni = 0; ni < 2; ++ni)
            #pragma unroll
            for (int kk = 0; kk < 2; ++kk)
                b0f[ni][kk] = *(const short8*)&Bs[d][wn >> 1][AOFF((wn & 1) * 64 + ni * 16 + r16, kk * 4 + kg)];
        if (more) { STAGE(As, A, aR0, aR1, nd, 0, kt + 1); STAGE(Bs, B, bR0, bR1, nd, 0, kt + 1); }
        BARRIER();
        LGKM0();
        __builtin_amdgcn_s_setprio(1);
        #pragma unroll
        for (int mi = 0; mi < 4; ++mi)
            #pragma unroll
            for (int ni = 0; ni < 2; ++ni)
                #pragma unroll
                for (int kk = 0; kk < 2; ++kk)
                    acc[mi][ni] = __builtin_amdgcn_mfma_f32_16x16x32_bf16(af[mi][kk], b0f[ni][kk], acc[mi][ni], 0, 0, 0);
        __builtin_amdgcn_s_setprio(0);
        BARRIER();

        // ---------------- P2: quadrant (mi 0-3, ni 2-3) ----------------
        #pragma unroll
        for (int ni = 0; ni < 2; ++ni)
            #pragma unroll
            for (int kk = 0; kk < 2; ++kk)
                b1f[ni][kk] = *(const short8*)&Bs[d][wn >> 1][AOFF((wn & 1) * 64 + (ni + 2) * 16 + r16, kk * 4 + kg)];
        if (more) { STAGE(As, A, aR0, aR1, nd, 1, kt + 1); STAGE(Bs, B, bR0, bR1, nd, 1, kt + 1); }
        BARRIER();
        LGKM0();
        __builtin_amdgcn_s_setprio(1);
        #pragma unroll
        for (int mi = 0; mi < 4; ++mi)
            #pragma unroll
            for (int ni = 0; ni < 2; ++ni)
                #pragma unroll
                for (int kk = 0; kk < 2; ++kk)
                    acc[mi][ni + 2] = __builtin_amdgcn_mfma_f32_16x16x32_bf16(af[mi][kk], b1f[ni][kk], acc[mi][ni + 2], 0, 0, 0);
        __builtin_amdgcn_s_setprio(0);
        BARRIER();

        // ---------------- P3: quadrant (mi 4-7, ni 2-3) ----------------
        #pragma unroll
        for (int mi = 0; mi < 4; ++mi)
            #pragma unroll
            for (int kk = 0; kk < 2; ++kk)
                af[mi][kk] = *(const short8*)&As[d][wm][AOFF((mi + 4) * 16 + r16, kk * 4 + kg)];
        BARRIER();
        LGKM0();
        __builtin_amdgcn_s_setprio(1);
        #pragma unroll
        for (int mi = 0; mi < 4; ++mi)
            #pragma unroll
            for (int ni = 0; ni < 2; ++ni)
                #pragma unroll
                for (int kk = 0; kk < 2; ++kk)
                    acc[mi + 4][ni + 2] = __builtin_amdgcn_mfma_f32_16x16x32_bf16(af[mi][kk], b1f[ni][kk], acc[mi + 4][ni + 2], 0, 0, 0);
        __builtin_amdgcn_s_setprio(0);
        BARRIER();

        // ---------------- P4: quadrant (mi 4-7, ni 0-1), all regs resident ----
        __builtin_amdgcn_s_setprio(1);
        #pragma unroll
        for (int mi = 0; mi < 4; ++mi)
            #pragma unroll
            for (int ni = 0; ni < 2; ++ni)
                #pragma unroll
                for (int kk = 0; kk < 2; ++kk)
                    acc[mi + 4][ni] = __builtin_amdgcn_mfma_f32_16x16x32_bf16(af[mi][kk], b0f[ni][kk], acc[mi + 4][ni], 0, 0, 0);
        __builtin_amdgcn_s_setprio(0);
        VMCNT0();      // next k-tile fully landed (issued >= 2 phases ago)
        BARRIER();
    }

    // epilogue: C rows = m0 + wm*128 + mi*16 + kg*4 + rr ; cols = n0 + wn*64 + ni*16 + r16
    #pragma unroll
    for (int mi = 0; mi < 8; ++mi)
        #pragma unroll
        for (int ni = 0; ni < 4; ++ni) {
            const int row = m0 + wm * 128 + mi * 16 + kg * 4;
            const int col = n0 + wn * 64 + ni * 16 + r16;
            f32x4 v = acc[mi][ni];
            #pragma unroll
            for (int rr = 0; rr < 4; ++rr) {
                const size_t o = (size_t)(row + rr) * ldC + col;
                if constexpr (MODE == 0) {
                    Cb[o] = f2bf(v[rr]);
                } else if constexpr (MODE == 1) {
                    float u = __uint_as_float((unsigned)Cb[o] << 16);
                    float g = v[rr];
                    float s = g / (1.0f + __expf(-g));
                    Cb[o] = f2bf(s * u);
                } else {
                    Cf[o] = v[rr];
                }
            }
        }
}

extern "C" void kernel_launch(void* const* d_in, const int* in_sizes, int n_in,
                              void* d_out, int out_size, void* d_ws, size_t ws_size,
                              hipStream_t stream) {
    const float* x  = (const float*)d_in[0];
    const float* wg = (const float*)d_in[1];
    const float* wu = (const float*)d_in[2];
    const float* wd = (const float*)d_in[3];
    float* out = (float*)d_out;

    // ws layout (total 494.0 MB — identical footprint to the round-2 proven fit):
    // [inter: Md*Id bf16 = 180.4MB][xb: Md*Hd][wgb: Id*Hd][wub: Id*Hd][wdb: Id*Hd]
    unsigned short* inter = (unsigned short*)d_ws;
    unsigned short* xb  = (unsigned short*)((char*)d_ws + (size_t)Md * Id * 2);
    unsigned short* wgb = xb  + (size_t)Md * Hd;
    unsigned short* wub = wgb + (size_t)Id * Hd;
    unsigned short* wdb = wub + (size_t)Id * Hd;

    k_cvt<<<dim3(2048), dim3(256), 0, stream>>>(x,  xb,  Md * Hd / 8);
    k_cvt<<<dim3(2048), dim3(256), 0, stream>>>(wg, wgb, Id * Hd / 8);
    k_cvt<<<dim3(2048), dim3(256), 0, stream>>>(wu, wub, Id * Hd / 8);
    k_cvt<<<dim3(2048), dim3(256), 0, stream>>>(wd, wdb, Id * Hd / 8);

    // up: inter = x . wu^T
    gemm8p<0><<<dim3((Md / 256) * (Id / 256)), dim3(512), 0, stream>>>(xb, wub, inter, nullptr, Hd, Id);
    // gate + SwiGLU: inter = silu(x . wg^T) * inter
    gemm8p<1><<<dim3((Md / 256) * (Id / 256)), dim3(512), 0, stream>>>(xb, wgb, inter, nullptr, Hd, Id);
    // down: out = inter . wd^T
    gemm8p<2><<<dim3((Md / 256) * (Hd / 256)), dim3(512), 0, stream>>>(inter, wdb, nullptr, out, Id, Hd);
}

// Round 4
// 2836.048 us; speedup vs baseline: 1.0978x; 1.0978x over previous
//
#include <hip/hip_runtime.h>
#include <hip/hip_bf16.h>
#include <stdint.h>

// B,S,H,I = 4,2048,4096,11008 ; M = B*S = 8192
static constexpr int Hd = 4096;
static constexpr int Id = 11008;
static constexpr int Md = 8192;

using short8 = __attribute__((ext_vector_type(8))) short;
using f32x4  = __attribute__((ext_vector_type(4))) float;

__device__ __forceinline__ unsigned short f2bf(float x) {
    union { float f; unsigned u; } v; v.f = x;
    unsigned r = v.u + 0x7FFF + ((v.u >> 16) & 1);   // RNE
    return (unsigned short)(r >> 16);
}

typedef const __attribute__((address_space(1))) unsigned int* as1_u32p;
typedef __attribute__((address_space(3))) unsigned int* as3_u32p;

__device__ __forceinline__ void gload16(const unsigned short* g, unsigned short* l) {
    __builtin_amdgcn_global_load_lds((as1_u32p)(const void*)g, (as3_u32p)(void*)l, 16, 0, 0);
}

// swizzled chunk offset (ushort index) within a [128 rows][64 cols] bf16 half-tile.
// chunk = 8 shorts (16B); 8 chunks per row; XOR row&7 into chunk-col.
#define AOFF(r, c) ((((r) * 8) + ((c) ^ ((r) & 7))) * 8)

#define LGKM0() do { asm volatile("s_waitcnt lgkmcnt(0)" ::: "memory"); \
                     __builtin_amdgcn_sched_barrier(0); } while (0)
#define VMCNT(n) do { asm volatile("s_waitcnt vmcnt(" #n ")" ::: "memory"); \
                      __builtin_amdgcn_sched_barrier(0); } while (0)
#define BARRIER() do { asm volatile("" ::: "memory"); __builtin_amdgcn_s_barrier(); \
                       asm volatile("" ::: "memory"); } while (0)

// stage one 128x64 half-tile of operand X into LDS (2 global_load_lds per thread)
#define STAGE(Xs, Xb, xR0, xR1, dd, h, kt) do {                                  \
    const size_t ho_ = (size_t)(h) * 128 * K + (size_t)(kt) * 64;                \
    gload16(Xb + xR0 + ho_, &Xs[dd][h][wave * 512]);                             \
    gload16(Xb + xR1 + ho_, &Xs[dd][h][4096 + wave * 512]);                      \
} while (0)

// ---------------------------------------------------------------------------
// fp32 -> bf16 bulk converter
// ---------------------------------------------------------------------------
__global__ __launch_bounds__(256) void k_cvt(const float* __restrict__ in,
                                             unsigned short* __restrict__ out, int n8) {
    int i = blockIdx.x * blockDim.x + threadIdx.x;
    const int stride = gridDim.x * blockDim.x;
    for (; i < n8; i += stride) {
        f32x4 a = *(const f32x4*)(in + (size_t)i * 8);
        f32x4 b = *(const f32x4*)(in + (size_t)i * 8 + 4);
        short8 v;
        v[0] = (short)f2bf(a[0]); v[1] = (short)f2bf(a[1]);
        v[2] = (short)f2bf(a[2]); v[3] = (short)f2bf(a[3]);
        v[4] = (short)f2bf(b[0]); v[5] = (short)f2bf(b[1]);
        v[6] = (short)f2bf(b[2]); v[7] = (short)f2bf(b[3]);
        *reinterpret_cast<short8*>(out + (size_t)i * 8) = v;
    }
}

// ---------------------------------------------------------------------------
// 256x256-tile, BK=64, 8-wave (2Mx4N), 4-phase GEMM with 2-tile-deep prefetch
// and counted vmcnt (T3+T4): C = A (MxK) . B^T (NxK)
// MODE 0: Cb[row*ldC+col] = bf16(acc)                  (up proj)
// MODE 1: Cb[..] = bf16( silu(acc) * bf2f(Cb[..]) )    (gate proj, RMW SwiGLU)
// MODE 2: Cf[..] = acc                                 (down proj, fp32 out)
//
// Staging discipline (race-free by construction):
//   iter kt reads dbuf d = kt&1; tile kt+2 is staged INTO dbuf d:
//     B-halves issued at P3 start (Bs[d] last ds_read completes at P2 LGKM0,
//       and every wave crossed the P2-end barrier before any P3 issue),
//     A-halves issued at P4 start (As[d] last ds_read completes at P3 LGKM0).
//   P4 ends with vmcnt(8): waits tile kt+1's 8 loads (issued ~7 phases ago),
//   leaves tile kt+2's 8 in flight across the barrier. Never drains to 0
//   except the final two iterations.
// ---------------------------------------------------------------------------
template<int MODE>
__global__ __launch_bounds__(512, 2) void gemm8p(
    const unsigned short* __restrict__ A, const unsigned short* __restrict__ B,
    unsigned short* __restrict__ Cb, float* __restrict__ Cf,
    const int K, const int ldC)
{
    __shared__ unsigned short As[2][2][8192];   // [dbuf][half][128*64]
    __shared__ unsigned short Bs[2][2][8192];   // 128 KiB total

    const int tid  = threadIdx.x;
    const int wave = tid >> 6;
    const int lane = tid & 63;
    const int wm   = wave >> 2;          // 0..1 -> C rows wm*128
    const int wn   = wave & 3;           // 0..3 -> C cols wn*64
    const int r16  = lane & 15;
    const int kg   = lane >> 4;          // 0..3

    const int nwg = gridDim.x;           // divisible by 8
    const int bid = blockIdx.x;
    const int swz = (bid & 7) * (nwg >> 3) + (bid >> 3);   // XCD swizzle (bijective)
    const int m0  = (swz & 31) * 256;    // M/256 = 32 tiles, m-fastest
    const int n0  = (swz >> 5) * 256;

    // staging coords: thread covers chunks {tid, 512+tid} of each half-tile
    const int i0 = tid,       r0 = i0 >> 3;
    const int i1 = 512 + tid, r1 = i1 >> 3;
    const int cc0 = (i0 & 7) ^ (r0 & 7);   // pre-swizzled source chunk-col
    const int cc1 = (i1 & 7) ^ (r1 & 7);
    const size_t aR0 = (size_t)(m0 + r0) * K + cc0 * 8;
    const size_t aR1 = (size_t)(m0 + r1) * K + cc1 * 8;
    const size_t bR0 = (size_t)(n0 + r0) * K + cc0 * 8;
    const size_t bR1 = (size_t)(n0 + r1) * K + cc1 * 8;

    f32x4 acc[8][4] = {};
    short8 af[4][2], b0f[2][2], b1f[2][2];

    const int NT = K >> 6;

    // prologue: stage tile 0 -> dbuf0, tile 1 -> dbuf1 (8 loads/thread each)
    STAGE(As, A, aR0, aR1, 0, 0, 0);
    STAGE(As, A, aR0, aR1, 0, 1, 0);
    STAGE(Bs, B, bR0, bR1, 0, 0, 0);
    STAGE(Bs, B, bR0, bR1, 0, 1, 0);
    if (NT > 1) {
        STAGE(As, A, aR0, aR1, 1, 0, 1);
        STAGE(As, A, aR0, aR1, 1, 1, 1);
        STAGE(Bs, B, bR0, bR1, 1, 0, 1);
        STAGE(Bs, B, bR0, bR1, 1, 1, 1);
        VMCNT(8);          // tile 0 landed; tile 1 still in flight
    } else {
        VMCNT(0);
    }
    BARRIER();

    for (int kt = 0; kt < NT; ++kt) {
        const int d  = kt & 1;
        const bool pf = (kt + 2) < NT;

        // ---------------- P1: quadrant (mi 0-3, ni 0-1) ----------------
        #pragma unroll
        for (int mi = 0; mi < 4; ++mi)
            #pragma unroll
            for (int kk = 0; kk < 2; ++kk)
                af[mi][kk] = *(const short8*)&As[d][wm][AOFF(mi * 16 + r16, kk * 4 + kg)];
        #pragma unroll
        for (int ni = 0; ni < 2; ++ni)
            #pragma unroll
            for (int kk = 0; kk < 2; ++kk)
                b0f[ni][kk] = *(const short8*)&Bs[d][wn >> 1][AOFF((wn & 1) * 64 + ni * 16 + r16, kk * 4 + kg)];
        BARRIER();
        LGKM0();
        __builtin_amdgcn_s_setprio(1);
        #pragma unroll
        for (int mi = 0; mi < 4; ++mi)
            #pragma unroll
            for (int ni = 0; ni < 2; ++ni)
                #pragma unroll
                for (int kk = 0; kk < 2; ++kk)
                    acc[mi][ni] = __builtin_amdgcn_mfma_f32_16x16x32_bf16(af[mi][kk], b0f[ni][kk], acc[mi][ni], 0, 0, 0);
        __builtin_amdgcn_s_setprio(0);
        BARRIER();

        // ---------------- P2: quadrant (mi 0-3, ni 2-3) ----------------
        #pragma unroll
        for (int ni = 0; ni < 2; ++ni)
            #pragma unroll
            for (int kk = 0; kk < 2; ++kk)
                b1f[ni][kk] = *(const short8*)&Bs[d][wn >> 1][AOFF((wn & 1) * 64 + (ni + 2) * 16 + r16, kk * 4 + kg)];
        BARRIER();
        LGKM0();
        __builtin_amdgcn_s_setprio(1);
        #pragma unroll
        for (int mi = 0; mi < 4; ++mi)
            #pragma unroll
            for (int ni = 0; ni < 2; ++ni)
                #pragma unroll
                for (int kk = 0; kk < 2; ++kk)
                    acc[mi][ni + 2] = __builtin_amdgcn_mfma_f32_16x16x32_bf16(af[mi][kk], b1f[ni][kk], acc[mi][ni + 2], 0, 0, 0);
        __builtin_amdgcn_s_setprio(0);
        BARRIER();

        // ---------------- P3: quadrant (mi 4-7, ni 2-3); stage B(kt+2) -> Bs[d] ----
        #pragma unroll
        for (int mi = 0; mi < 4; ++mi)
            #pragma unroll
            for (int kk = 0; kk < 2; ++kk)
                af[mi][kk] = *(const short8*)&As[d][wm][AOFF((mi + 4) * 16 + r16, kk * 4 + kg)];
        if (pf) {
            STAGE(Bs, B, bR0, bR1, d, 0, kt + 2);
            STAGE(Bs, B, bR0, bR1, d, 1, kt + 2);
        }
        BARRIER();
        LGKM0();
        __builtin_amdgcn_s_setprio(1);
        #pragma unroll
        for (int mi = 0; mi < 4; ++mi)
            #pragma unroll
            for (int ni = 0; ni < 2; ++ni)
                #pragma unroll
                for (int kk = 0; kk < 2; ++kk)
                    acc[mi + 4][ni + 2] = __builtin_amdgcn_mfma_f32_16x16x32_bf16(af[mi][kk], b1f[ni][kk], acc[mi + 4][ni + 2], 0, 0, 0);
        __builtin_amdgcn_s_setprio(0);
        BARRIER();

        // ---------------- P4: quadrant (mi 4-7, ni 0-1); stage A(kt+2) -> As[d] ----
        if (pf) {
            STAGE(As, A, aR0, aR1, d, 0, kt + 2);
            STAGE(As, A, aR0, aR1, d, 1, kt + 2);
        }
        __builtin_amdgcn_s_setprio(1);
        #pragma unroll
        for (int mi = 0; mi < 4; ++mi)
            #pragma unroll
            for (int ni = 0; ni < 2; ++ni)
                #pragma unroll
                for (int kk = 0; kk < 2; ++kk)
                    acc[mi + 4][ni] = __builtin_amdgcn_mfma_f32_16x16x32_bf16(af[mi][kk], b0f[ni][kk], acc[mi + 4][ni], 0, 0, 0);
        __builtin_amdgcn_s_setprio(0);
        if (pf) { VMCNT(8); }   // tile kt+1 landed; kt+2 stays in flight
        else    { VMCNT(0); }   // tail: drain
        BARRIER();
    }

    // epilogue: C rows = m0 + wm*128 + mi*16 + kg*4 + rr ; cols = n0 + wn*64 + ni*16 + r16
    #pragma unroll
    for (int mi = 0; mi < 8; ++mi)
        #pragma unroll
        for (int ni = 0; ni < 4; ++ni) {
            const int row = m0 + wm * 128 + mi * 16 + kg * 4;
            const int col = n0 + wn * 64 + ni * 16 + r16;
            f32x4 v = acc[mi][ni];
            #pragma unroll
            for (int rr = 0; rr < 4; ++rr) {
                const size_t o = (size_t)(row + rr) * ldC + col;
                if constexpr (MODE == 0) {
                    Cb[o] = f2bf(v[rr]);
                } else if constexpr (MODE == 1) {
                    float u = __uint_as_float((unsigned)Cb[o] << 16);
                    float g = v[rr];
                    float s = g / (1.0f + __expf(-g));
                    Cb[o] = f2bf(s * u);
                } else {
                    Cf[o] = v[rr];
                }
            }
        }
}

extern "C" void kernel_launch(void* const* d_in, const int* in_sizes, int n_in,
                              void* d_out, int out_size, void* d_ws, size_t ws_size,
                              hipStream_t stream) {
    const float* x  = (const float*)d_in[0];
    const float* wg = (const float*)d_in[1];
    const float* wu = (const float*)d_in[2];
    const float* wd = (const float*)d_in[3];
    float* out = (float*)d_out;

    // ws layout (total 494.0 MB):
    // [inter: Md*Id bf16 = 180.4MB][xb: Md*Hd][wgb: Id*Hd][wub: Id*Hd][wdb: Id*Hd]
    unsigned short* inter = (unsigned short*)d_ws;
    unsigned short* xb  = (unsigned short*)((char*)d_ws + (size_t)Md * Id * 2);
    unsigned short* wgb = xb  + (size_t)Md * Hd;
    unsigned short* wub = wgb + (size_t)Id * Hd;
    unsigned short* wdb = wub + (size_t)Id * Hd;

    k_cvt<<<dim3(2048), dim3(256), 0, stream>>>(x,  xb,  Md * Hd / 8);
    k_cvt<<<dim3(2048), dim3(256), 0, stream>>>(wg, wgb, Id * Hd / 8);
    k_cvt<<<dim3(2048), dim3(256), 0, stream>>>(wu, wub, Id * Hd / 8);
    k_cvt<<<dim3(2048), dim3(256), 0, stream>>>(wd, wdb, Id * Hd / 8);

    // up: inter = x . wu^T
    gemm8p<0><<<dim3((Md / 256) * (Id / 256)), dim3(512), 0, stream>>>(xb, wub, inter, nullptr, Hd, Id);
    // gate + SwiGLU: inter = silu(x . wg^T) * inter
    gemm8p<1><<<dim3((Md / 256) * (Id / 256)), dim3(512), 0, stream>>>(xb, wgb, inter, nullptr, Hd, Id);
    // down: out = inter . wd^T
    gemm8p<2><<<dim3((Md / 256) * (Hd / 256)), dim3(512), 0, stream>>>(inter, wdb, nullptr, out, Id, Hd);
}

// Round 5
// 2713.258 us; speedup vs baseline: 1.1474x; 1.0453x over previous
//
#include <hip/hip_runtime.h>
#include <hip/hip_bf16.h>
#include <stdint.h>

// B,S,H,I = 4,2048,4096,11008 ; M = B*S = 8192
static constexpr int Hd = 4096;
static constexpr int Id = 11008;
static constexpr int Md = 8192;

using short8 = __attribute__((ext_vector_type(8))) short;
using f32x4  = __attribute__((ext_vector_type(4))) float;

__device__ __forceinline__ unsigned short f2bf(float x) {
    union { float f; unsigned u; } v; v.f = x;
    unsigned r = v.u + 0x7FFF + ((v.u >> 16) & 1);   // RNE
    return (unsigned short)(r >> 16);
}

typedef const __attribute__((address_space(1))) unsigned int* as1_u32p;
typedef __attribute__((address_space(3))) unsigned int* as3_u32p;

__device__ __forceinline__ void gload16(const unsigned short* g, unsigned short* l) {
    __builtin_amdgcn_global_load_lds((as1_u32p)(const void*)g, (as3_u32p)(void*)l, 16, 0, 0);
}

// swizzled chunk offset (ushort index) within a [128 rows][64 cols] bf16 half-tile.
// chunk = 8 shorts (16B); 8 chunks per row; XOR row&7 into chunk-col.
#define AOFF(r, c) ((((r) * 8) + ((c) ^ ((r) & 7))) * 8)

#define LGKM0() do { asm volatile("s_waitcnt lgkmcnt(0)" ::: "memory"); \
                     __builtin_amdgcn_sched_barrier(0); } while (0)
#define VMCNT(n) do { asm volatile("s_waitcnt vmcnt(" #n ")" ::: "memory"); \
                      __builtin_amdgcn_sched_barrier(0); } while (0)
#define BARRIER() do { asm volatile("" ::: "memory"); __builtin_amdgcn_s_barrier(); \
                       asm volatile("" ::: "memory"); } while (0)

// ---------------------------------------------------------------------------
// fp32 -> bf16 bulk converter
// ---------------------------------------------------------------------------
__global__ __launch_bounds__(256) void k_cvt(const float* __restrict__ in,
                                             unsigned short* __restrict__ out, int n8) {
    int i = blockIdx.x * blockDim.x + threadIdx.x;
    const int stride = gridDim.x * blockDim.x;
    for (; i < n8; i += stride) {
        f32x4 a = *(const f32x4*)(in + (size_t)i * 8);
        f32x4 b = *(const f32x4*)(in + (size_t)i * 8 + 4);
        short8 v;
        v[0] = (short)f2bf(a[0]); v[1] = (short)f2bf(a[1]);
        v[2] = (short)f2bf(a[2]); v[3] = (short)f2bf(a[3]);
        v[4] = (short)f2bf(b[0]); v[5] = (short)f2bf(b[1]);
        v[6] = (short)f2bf(b[2]); v[7] = (short)f2bf(b[3]);
        *reinterpret_cast<short8*>(out + (size_t)i * 8) = v;
    }
}

// ---------------------------------------------------------------------------
// One K-tile body (4 phases), dbuf index D is a COMPILE-TIME literal so every
// ds_read is base+immediate. Stage of tile (this+2) into buf D via pointer
// + literal element offset stoff (128 for body0, 192 for body1).
// Sync skeleton identical to the verified R4 kernel.
// ---------------------------------------------------------------------------
template<int D>
__device__ __forceinline__ void ktile_body(
    unsigned short (&As)[2][2][8192], unsigned short (&Bs)[2][2][8192],
    const unsigned short* pA0, const unsigned short* pA1,
    const unsigned short* pB0, const unsigned short* pB1,
    size_t hK, int stoff, bool pf,
    int wm, int wn, int r16, int kg, int wave,
    f32x4 (&acc)[8][4], short8 (&af)[4][2], short8 (&b0f)[2][2], short8 (&b1f)[2][2])
{
    // ---------------- P1: quadrant (mi 0-3, ni 0-1) ----------------
    #pragma unroll
    for (int mi = 0; mi < 4; ++mi)
        #pragma unroll
        for (int kk = 0; kk < 2; ++kk)
            af[mi][kk] = *(const short8*)&As[D][wm][AOFF(mi * 16 + r16, kk * 4 + kg)];
    #pragma unroll
    for (int ni = 0; ni < 2; ++ni)
        #pragma unroll
        for (int kk = 0; kk < 2; ++kk)
            b0f[ni][kk] = *(const short8*)&Bs[D][wn >> 1][AOFF((wn & 1) * 64 + ni * 16 + r16, kk * 4 + kg)];
    BARRIER();
    LGKM0();
    __builtin_amdgcn_s_setprio(1);
    #pragma unroll
    for (int mi = 0; mi < 4; ++mi)
        #pragma unroll
        for (int ni = 0; ni < 2; ++ni)
            #pragma unroll
            for (int kk = 0; kk < 2; ++kk)
                acc[mi][ni] = __builtin_amdgcn_mfma_f32_16x16x32_bf16(af[mi][kk], b0f[ni][kk], acc[mi][ni], 0, 0, 0);
    __builtin_amdgcn_s_setprio(0);
    BARRIER();

    // ---------------- P2: quadrant (mi 0-3, ni 2-3) ----------------
    #pragma unroll
    for (int ni = 0; ni < 2; ++ni)
        #pragma unroll
        for (int kk = 0; kk < 2; ++kk)
            b1f[ni][kk] = *(const short8*)&Bs[D][wn >> 1][AOFF((wn & 1) * 64 + (ni + 2) * 16 + r16, kk * 4 + kg)];
    BARRIER();
    LGKM0();
    __builtin_amdgcn_s_setprio(1);
    #pragma unroll
    for (int mi = 0; mi < 4; ++mi)
        #pragma unroll
        for (int ni = 0; ni < 2; ++ni)
            #pragma unroll
            for (int kk = 0; kk < 2; ++kk)
                acc[mi][ni + 2] = __builtin_amdgcn_mfma_f32_16x16x32_bf16(af[mi][kk], b1f[ni][kk], acc[mi][ni + 2], 0, 0, 0);
    __builtin_amdgcn_s_setprio(0);
    BARRIER();

    // ---------------- P3: quadrant (mi 4-7, ni 2-3); stage B(+2) -> Bs[D] ----
    #pragma unroll
    for (int mi = 0; mi < 4; ++mi)
        #pragma unroll
        for (int kk = 0; kk < 2; ++kk)
            af[mi][kk] = *(const short8*)&As[D][wm][AOFF((mi + 4) * 16 + r16, kk * 4 + kg)];
    if (pf) {
        gload16(pB0 + stoff,      &Bs[D][0][wave * 512]);
        gload16(pB1 + stoff,      &Bs[D][0][4096 + wave * 512]);
        gload16(pB0 + hK + stoff, &Bs[D][1][wave * 512]);
        gload16(pB1 + hK + stoff, &Bs[D][1][4096 + wave * 512]);
    }
    BARRIER();
    LGKM0();
    __builtin_amdgcn_s_setprio(1);
    #pragma unroll
    for (int mi = 0; mi < 4; ++mi)
        #pragma unroll
        for (int ni = 0; ni < 2; ++ni)
            #pragma unroll
            for (int kk = 0; kk < 2; ++kk)
                acc[mi + 4][ni + 2] = __builtin_amdgcn_mfma_f32_16x16x32_bf16(af[mi][kk], b1f[ni][kk], acc[mi + 4][ni + 2], 0, 0, 0);
    __builtin_amdgcn_s_setprio(0);
    BARRIER();

    // ---------------- P4: quadrant (mi 4-7, ni 0-1); stage A(+2) -> As[D] ----
    if (pf) {
        gload16(pA0 + stoff,      &As[D][0][wave * 512]);
        gload16(pA1 + stoff,      &As[D][0][4096 + wave * 512]);
        gload16(pA0 + hK + stoff, &As[D][1][wave * 512]);
        gload16(pA1 + hK + stoff, &As[D][1][4096 + wave * 512]);
    }
    __builtin_amdgcn_s_setprio(1);
    #pragma unroll
    for (int mi = 0; mi < 4; ++mi)
        #pragma unroll
        for (int ni = 0; ni < 2; ++ni)
            #pragma unroll
            for (int kk = 0; kk < 2; ++kk)
                acc[mi + 4][ni] = __builtin_amdgcn_mfma_f32_16x16x32_bf16(af[mi][kk], b0f[ni][kk], acc[mi + 4][ni], 0, 0, 0);
    __builtin_amdgcn_s_setprio(0);
    if (pf) { VMCNT(8); }   // tile (this+1) landed; (this+2) stays in flight
    else    { VMCNT(0); }   // tail: drain
    BARRIER();
}

// ---------------------------------------------------------------------------
// 256x256-tile, BK=64, 8-wave (2Mx4N), 4-phase GEMM, 2-tile-deep prefetch,
// counted vmcnt, K-loop unrolled x2 (compile-time dbuf): C = A (MxK) . B^T (NxK)
// MODE 0: Cb[..] = bf16(acc)                  (up proj)
// MODE 1: Cb[..] = bf16( silu(acc) * bf2f(Cb[..]) )    (gate proj, RMW SwiGLU)
// MODE 2: Cf[..] = acc                                 (down proj, fp32 out)
// ---------------------------------------------------------------------------
template<int MODE>
__global__ __launch_bounds__(512, 2) void gemm8p(
    const unsigned short* __restrict__ A, const unsigned short* __restrict__ B,
    unsigned short* __restrict__ Cb, float* __restrict__ Cf,
    const int K, const int ldC)
{
    __shared__ unsigned short As[2][2][8192];   // [dbuf][half][128*64]
    __shared__ unsigned short Bs[2][2][8192];   // 128 KiB total

    const int tid  = threadIdx.x;
    const int wave = tid >> 6;
    const int lane = tid & 63;
    const int wm   = wave >> 2;          // 0..1 -> C rows wm*128
    const int wn   = wave & 3;           // 0..3 -> C cols wn*64
    const int r16  = lane & 15;
    const int kg   = lane >> 4;          // 0..3

    const int nwg = gridDim.x;           // divisible by 8
    const int bid = blockIdx.x;
    const int swz = (bid & 7) * (nwg >> 3) + (bid >> 3);   // XCD swizzle (bijective)
    const int m0  = (swz & 31) * 256;    // M/256 = 32 tiles, m-fastest
    const int n0  = (swz >> 5) * 256;

    // staging coords: thread covers chunks {tid, 512+tid} of each half-tile
    const int i0 = tid,       r0 = i0 >> 3;
    const int i1 = 512 + tid, r1 = i1 >> 3;
    const int cc0 = (i0 & 7) ^ (r0 & 7);   // pre-swizzled source chunk-col
    const int cc1 = (i1 & 7) ^ (r1 & 7);
    const size_t hK = (size_t)128 * K;     // half-tile row offset (h=1)

    // per-thread staging pointers (advance by 128 elems per unrolled pair)
    const unsigned short* pA0 = A + (size_t)(m0 + r0) * K + cc0 * 8;
    const unsigned short* pA1 = A + (size_t)(m0 + r1) * K + cc1 * 8;
    const unsigned short* pB0 = B + (size_t)(n0 + r0) * K + cc0 * 8;
    const unsigned short* pB1 = B + (size_t)(n0 + r1) * K + cc1 * 8;

    f32x4 acc[8][4] = {};
    short8 af[4][2], b0f[2][2], b1f[2][2];

    const int NT = K >> 6;   // even for K=4096 (64) and K=11008 (172)

    // prologue: stage tile 0 -> dbuf0, tile 1 -> dbuf1 (8 loads/thread each)
    gload16(pA0,      &As[0][0][wave * 512]);
    gload16(pA1,      &As[0][0][4096 + wave * 512]);
    gload16(pA0 + hK, &As[0][1][wave * 512]);
    gload16(pA1 + hK, &As[0][1][4096 + wave * 512]);
    gload16(pB0,      &Bs[0][0][wave * 512]);
    gload16(pB1,      &Bs[0][0][4096 + wave * 512]);
    gload16(pB0 + hK, &Bs[0][1][wave * 512]);
    gload16(pB1 + hK, &Bs[0][1][4096 + wave * 512]);
    gload16(pA0 + 64,      &As[1][0][wave * 512]);
    gload16(pA1 + 64,      &As[1][0][4096 + wave * 512]);
    gload16(pA0 + hK + 64, &As[1][1][wave * 512]);
    gload16(pA1 + hK + 64, &As[1][1][4096 + wave * 512]);
    gload16(pB0 + 64,      &Bs[1][0][wave * 512]);
    gload16(pB1 + 64,      &Bs[1][0][4096 + wave * 512]);
    gload16(pB0 + hK + 64, &Bs[1][1][wave * 512]);
    gload16(pB1 + hK + 64, &Bs[1][1][4096 + wave * 512]);
    VMCNT(8);          // tile 0 landed; tile 1 still in flight
    BARRIER();

    for (int kt = 0; kt < NT; kt += 2) {
        const bool pf0 = (kt + 2) < NT;
        const bool pf1 = (kt + 3) < NT;
        ktile_body<0>(As, Bs, pA0, pA1, pB0, pB1, hK, 128, pf0,
                      wm, wn, r16, kg, wave, acc, af, b0f, b1f);
        ktile_body<1>(As, Bs, pA0, pA1, pB0, pB1, hK, 192, pf1,
                      wm, wn, r16, kg, wave, acc, af, b0f, b1f);
        pA0 += 128; pA1 += 128; pB0 += 128; pB1 += 128;
    }

    // epilogue: C rows = m0 + wm*128 + mi*16 + kg*4 + rr ; cols = n0 + wn*64 + ni*16 + r16
    #pragma unroll
    for (int mi = 0; mi < 8; ++mi)
        #pragma unroll
        for (int ni = 0; ni < 4; ++ni) {
            const int row = m0 + wm * 128 + mi * 16 + kg * 4;
            const int col = n0 + wn * 64 + ni * 16 + r16;
            f32x4 v = acc[mi][ni];
            #pragma unroll
            for (int rr = 0; rr < 4; ++rr) {
                const size_t o = (size_t)(row + rr) * ldC + col;
                if constexpr (MODE == 0) {
                    Cb[o] = f2bf(v[rr]);
                } else if constexpr (MODE == 1) {
                    float u = __uint_as_float((unsigned)Cb[o] << 16);
                    float g = v[rr];
                    float s = g / (1.0f + __expf(-g));
                    Cb[o] = f2bf(s * u);
                } else {
                    Cf[o] = v[rr];
                }
            }
        }
}

extern "C" void kernel_launch(void* const* d_in, const int* in_sizes, int n_in,
                              void* d_out, int out_size, void* d_ws, size_t ws_size,
                              hipStream_t stream) {
    const float* x  = (const float*)d_in[0];
    const float* wg = (const float*)d_in[1];
    const float* wu = (const float*)d_in[2];
    const float* wd = (const float*)d_in[3];
    float* out = (float*)d_out;

    // ws layout (total 494.0 MB):
    // [inter: Md*Id bf16 = 180.4MB][xb: Md*Hd][wgb: Id*Hd][wub: Id*Hd][wdb: Id*Hd]
    unsigned short* inter = (unsigned short*)d_ws;
    unsigned short* xb  = (unsigned short*)((char*)d_ws + (size_t)Md * Id * 2);
    unsigned short* wgb = xb  + (size_t)Md * Hd;
    unsigned short* wub = wgb + (size_t)Id * Hd;
    unsigned short* wdb = wub + (size_t)Id * Hd;

    k_cvt<<<dim3(2048), dim3(256), 0, stream>>>(x,  xb,  Md * Hd / 8);
    k_cvt<<<dim3(2048), dim3(256), 0, stream>>>(wg, wgb, Id * Hd / 8);
    k_cvt<<<dim3(2048), dim3(256), 0, stream>>>(wu, wub, Id * Hd / 8);
    k_cvt<<<dim3(2048), dim3(256), 0, stream>>>(wd, wdb, Id * Hd / 8);

    // up: inter = x . wu^T
    gemm8p<0><<<dim3((Md / 256) * (Id / 256)), dim3(512), 0, stream>>>(xb, wub, inter, nullptr, Hd, Id);
    // gate + SwiGLU: inter = silu(x . wg^T) * inter
    gemm8p<1><<<dim3((Md / 256) * (Id / 256)), dim3(512), 0, stream>>>(xb, wgb, inter, nullptr, Hd, Id);
    // down: out = inter . wd^T
    gemm8p<2><<<dim3((Md / 256) * (Hd / 256)), dim3(512), 0, stream>>>(inter, wdb, nullptr, out, Id, Hd);
}

// Round 6
// 2262.859 us; speedup vs baseline: 1.3758x; 1.1990x over previous
//
#include <hip/hip_runtime.h>
#include <hip/hip_bf16.h>
#include <stdint.h>

// B,S,H,I = 4,2048,4096,11008 ; M = B*S = 8192
static constexpr int Hd = 4096;
static constexpr int Id = 11008;
static constexpr int Md = 8192;

using short8 = __attribute__((ext_vector_type(8))) short;
using f32x4  = __attribute__((ext_vector_type(4))) float;

__device__ __forceinline__ unsigned short f2bf(float x) {
    union { float f; unsigned u; } v; v.f = x;
    unsigned r = v.u + 0x7FFF + ((v.u >> 16) & 1);   // RNE
    return (unsigned short)(r >> 16);
}

typedef const __attribute__((address_space(1))) unsigned int* as1_u32p;
typedef __attribute__((address_space(3))) unsigned int* as3_u32p;

__device__ __forceinline__ void gload16(const unsigned short* g, unsigned short* l) {
    __builtin_amdgcn_global_load_lds((as1_u32p)(const void*)g, (as3_u32p)(void*)l, 16, 0, 0);
}

// swizzled chunk offset (ushort index) within a [rows][64 cols] bf16 tile.
// chunk = 8 shorts (16B); 8 chunks per row; XOR row&7 into chunk-col.
#define AOFF(r, c) ((((r) * 8) + ((c) ^ ((r) & 7))) * 8)

#define LGKM0() do { asm volatile("s_waitcnt lgkmcnt(0)" ::: "memory"); \
                     __builtin_amdgcn_sched_barrier(0); } while (0)
#define VMCNT(n) do { asm volatile("s_waitcnt vmcnt(" #n ")" ::: "memory"); \
                      __builtin_amdgcn_sched_barrier(0); } while (0)
#define BARRIER() do { asm volatile("" ::: "memory"); __builtin_amdgcn_s_barrier(); \
                       asm volatile("" ::: "memory"); } while (0)

// ---------------------------------------------------------------------------
// fp32 -> bf16 bulk converter
// ---------------------------------------------------------------------------
__global__ __launch_bounds__(256) void k_cvt(const float* __restrict__ in,
                                             unsigned short* __restrict__ out, int n8) {
    int i = blockIdx.x * blockDim.x + threadIdx.x;
    const int stride = gridDim.x * blockDim.x;
    for (; i < n8; i += stride) {
        f32x4 a = *(const f32x4*)(in + (size_t)i * 8);
        f32x4 b = *(const f32x4*)(in + (size_t)i * 8 + 4);
        short8 v;
        v[0] = (short)f2bf(a[0]); v[1] = (short)f2bf(a[1]);
        v[2] = (short)f2bf(a[2]); v[3] = (short)f2bf(a[3]);
        v[4] = (short)f2bf(b[0]); v[5] = (short)f2bf(b[1]);
        v[6] = (short)f2bf(b[2]); v[7] = (short)f2bf(b[3]);
        *reinterpret_cast<short8*>(out + (size_t)i * 8) = v;
    }
}

// ===========================================================================
// FUSED up+gate kernel: inter[m,i] = silu(x.wg^T)[m,i] * (x.wu^T)[m,i]
// Block tile 256(m) x 128(i), BK=64, 8 waves (2m x 4n), wave tile 128x32 per
// matrix, dual accumulators, 4-phase pipelined, 2-tile-deep prefetch,
// counted vmcnt. K = Hd = 4096 (compile-time).
// ===========================================================================
template<int D>
__device__ __forceinline__ void ug_body(
    unsigned short (&As)[2][2][8192], unsigned short (&Gs)[2][8192], unsigned short (&Us)[2][8192],
    const unsigned short* pA0, const unsigned short* pA1,
    const unsigned short* pG0, const unsigned short* pG1,
    const unsigned short* pU0, const unsigned short* pU1,
    int stoff, bool pf,
    int wm, int wn, int r16, int kg, int wave,
    f32x4 (&accg)[8][2], f32x4 (&accu)[8][2])
{
    constexpr size_t hK = (size_t)128 * Hd;
    short8 af[4][2], gf[2][2], uf[2][2];

    // ---- P1: G quadrant mi 0-3 ----
    #pragma unroll
    for (int mi = 0; mi < 4; ++mi)
        #pragma unroll
        for (int kk = 0; kk < 2; ++kk)
            af[mi][kk] = *(const short8*)&As[D][wm][AOFF(mi * 16 + r16, kk * 4 + kg)];
    #pragma unroll
    for (int ni = 0; ni < 2; ++ni)
        #pragma unroll
        for (int kk = 0; kk < 2; ++kk)
            gf[ni][kk] = *(const short8*)&Gs[D][AOFF(wn * 32 + ni * 16 + r16, kk * 4 + kg)];
    BARRIER();
    LGKM0();
    __builtin_amdgcn_s_setprio(1);
    #pragma unroll
    for (int mi = 0; mi < 4; ++mi)
        #pragma unroll
        for (int ni = 0; ni < 2; ++ni)
            #pragma unroll
            for (int kk = 0; kk < 2; ++kk)
                accg[mi][ni] = __builtin_amdgcn_mfma_f32_16x16x32_bf16(af[mi][kk], gf[ni][kk], accg[mi][ni], 0, 0, 0);
    __builtin_amdgcn_s_setprio(0);
    BARRIER();

    // ---- P2: U quadrant mi 0-3 (af reuse); stage G(kt+2) ----
    #pragma unroll
    for (int ni = 0; ni < 2; ++ni)
        #pragma unroll
        for (int kk = 0; kk < 2; ++kk)
            uf[ni][kk] = *(const short8*)&Us[D][AOFF(wn * 32 + ni * 16 + r16, kk * 4 + kg)];
    if (pf) {
        gload16(pG0 + stoff, &Gs[D][wave * 512]);
        gload16(pG1 + stoff, &Gs[D][4096 + wave * 512]);
    }
    BARRIER();
    LGKM0();
    __builtin_amdgcn_s_setprio(1);
    #pragma unroll
    for (int mi = 0; mi < 4; ++mi)
        #pragma unroll
        for (int ni = 0; ni < 2; ++ni)
            #pragma unroll
            for (int kk = 0; kk < 2; ++kk)
                accu[mi][ni] = __builtin_amdgcn_mfma_f32_16x16x32_bf16(af[mi][kk], uf[ni][kk], accu[mi][ni], 0, 0, 0);
    __builtin_amdgcn_s_setprio(0);
    BARRIER();

    // ---- P3: G quadrant mi 4-7 (gf reuse); stage U(kt+2) ----
    #pragma unroll
    for (int mi = 0; mi < 4; ++mi)
        #pragma unroll
        for (int kk = 0; kk < 2; ++kk)
            af[mi][kk] = *(const short8*)&As[D][wm][AOFF((mi + 4) * 16 + r16, kk * 4 + kg)];
    if (pf) {
        gload16(pU0 + stoff, &Us[D][wave * 512]);
        gload16(pU1 + stoff, &Us[D][4096 + wave * 512]);
    }
    BARRIER();
    LGKM0();
    __builtin_amdgcn_s_setprio(1);
    #pragma unroll
    for (int mi = 0; mi < 4; ++mi)
        #pragma unroll
        for (int ni = 0; ni < 2; ++ni)
            #pragma unroll
            for (int kk = 0; kk < 2; ++kk)
                accg[mi + 4][ni] = __builtin_amdgcn_mfma_f32_16x16x32_bf16(af[mi][kk], gf[ni][kk], accg[mi + 4][ni], 0, 0, 0);
    __builtin_amdgcn_s_setprio(0);
    BARRIER();

    // ---- P4: U quadrant mi 4-7 (af+uf reuse); stage A(kt+2) ----
    if (pf) {
        gload16(pA0 + stoff,      &As[D][0][wave * 512]);
        gload16(pA1 + stoff,      &As[D][0][4096 + wave * 512]);
        gload16(pA0 + hK + stoff, &As[D][1][wave * 512]);
        gload16(pA1 + hK + stoff, &As[D][1][4096 + wave * 512]);
    }
    __builtin_amdgcn_s_setprio(1);
    #pragma unroll
    for (int mi = 0; mi < 4; ++mi)
        #pragma unroll
        for (int ni = 0; ni < 2; ++ni)
            #pragma unroll
            for (int kk = 0; kk < 2; ++kk)
                accu[mi + 4][ni] = __builtin_amdgcn_mfma_f32_16x16x32_bf16(af[mi][kk], uf[ni][kk], accu[mi + 4][ni], 0, 0, 0);
    __builtin_amdgcn_s_setprio(0);
    if (pf) { VMCNT(8); }   // tile (this+1) landed; (this+2) stays in flight
    else    { VMCNT(0); }
    BARRIER();
}

__global__ __launch_bounds__(512, 2) void k_upgate(
    const unsigned short* __restrict__ A,   // xb  [Md][Hd]
    const unsigned short* __restrict__ G,   // wgb [Id][Hd]
    const unsigned short* __restrict__ U,   // wub [Id][Hd]
    unsigned short* __restrict__ inter)     // [Md][Id]
{
    __shared__ unsigned short As[2][2][8192];  // 64 KiB: [dbuf][half][128*64]
    __shared__ unsigned short Gs[2][8192];     // 32 KiB: [dbuf][128*64]
    __shared__ unsigned short Us[2][8192];     // 32 KiB

    const int tid  = threadIdx.x;
    const int wave = tid >> 6;
    const int lane = tid & 63;
    const int wm   = wave >> 2;          // 0..1 -> rows wm*128
    const int wn   = wave & 3;           // 0..3 -> cols wn*32
    const int r16  = lane & 15;
    const int kg   = lane >> 4;

    const int nwg = gridDim.x;           // 2752, %8==0
    const int bid = blockIdx.x;
    const int swz = (bid & 7) * (nwg >> 3) + (bid >> 3);
    const int m0  = (swz & 31) * 256;    // 32 m-tiles, m-fastest
    const int n0  = (swz >> 5) * 128;    // 86 n-tiles

    const int i0 = tid,       r0 = i0 >> 3;
    const int i1 = 512 + tid, r1 = i1 >> 3;
    const int cc0 = (i0 & 7) ^ (r0 & 7);
    const int cc1 = (i1 & 7) ^ (r1 & 7);
    constexpr size_t hK = (size_t)128 * Hd;

    const unsigned short* pA0 = A + (size_t)(m0 + r0) * Hd + cc0 * 8;
    const unsigned short* pA1 = A + (size_t)(m0 + r1) * Hd + cc1 * 8;
    const unsigned short* pG0 = G + (size_t)(n0 + r0) * Hd + cc0 * 8;
    const unsigned short* pG1 = G + (size_t)(n0 + r1) * Hd + cc1 * 8;
    const unsigned short* pU0 = U + (size_t)(n0 + r0) * Hd + cc0 * 8;
    const unsigned short* pU1 = U + (size_t)(n0 + r1) * Hd + cc1 * 8;

    f32x4 accg[8][2] = {};
    f32x4 accu[8][2] = {};

    constexpr int NT = Hd >> 6;   // 64 (even)

    // prologue: tile 0 -> bufs[0], tile 1 -> bufs[1] (8 loads/thread each)
    gload16(pA0,      &As[0][0][wave * 512]);
    gload16(pA1,      &As[0][0][4096 + wave * 512]);
    gload16(pA0 + hK, &As[0][1][wave * 512]);
    gload16(pA1 + hK, &As[0][1][4096 + wave * 512]);
    gload16(pG0,      &Gs[0][wave * 512]);
    gload16(pG1,      &Gs[0][4096 + wave * 512]);
    gload16(pU0,      &Us[0][wave * 512]);
    gload16(pU1,      &Us[0][4096 + wave * 512]);
    gload16(pA0 + 64,      &As[1][0][wave * 512]);
    gload16(pA1 + 64,      &As[1][0][4096 + wave * 512]);
    gload16(pA0 + hK + 64, &As[1][1][wave * 512]);
    gload16(pA1 + hK + 64, &As[1][1][4096 + wave * 512]);
    gload16(pG0 + 64,      &Gs[1][wave * 512]);
    gload16(pG1 + 64,      &Gs[1][4096 + wave * 512]);
    gload16(pU0 + 64,      &Us[1][wave * 512]);
    gload16(pU1 + 64,      &Us[1][4096 + wave * 512]);
    VMCNT(8);
    BARRIER();

    for (int kt = 0; kt < NT; kt += 2) {
        const bool pf0 = (kt + 2) < NT;
        const bool pf1 = (kt + 3) < NT;
        ug_body<0>(As, Gs, Us, pA0, pA1, pG0, pG1, pU0, pU1, 128, pf0,
                   wm, wn, r16, kg, wave, accg, accu);
        ug_body<1>(As, Gs, Us, pA0, pA1, pG0, pG1, pU0, pU1, 192, pf1,
                   wm, wn, r16, kg, wave, accg, accu);
        pA0 += 128; pA1 += 128; pG0 += 128; pG1 += 128; pU0 += 128; pU1 += 128;
    }

    // epilogue: in-register SwiGLU, single write of inter
    #pragma unroll
    for (int mi = 0; mi < 8; ++mi)
        #pragma unroll
        for (int ni = 0; ni < 2; ++ni) {
            const int row = m0 + wm * 128 + mi * 16 + kg * 4;
            const int col = n0 + wn * 32 + ni * 16 + r16;
            f32x4 g = accg[mi][ni], u = accu[mi][ni];
            #pragma unroll
            for (int rr = 0; rr < 4; ++rr) {
                float gv = g[rr];
                float s  = gv / (1.0f + __expf(-gv));
                inter[(size_t)(row + rr) * Id + col] = f2bf(s * u[rr]);
            }
        }
}

// ===========================================================================
// Down GEMM (unchanged proven R5 structure): out = inter . wd^T, fp32 out
// 256x256 tile, BK=64, 8 waves, 4-phase, 2-tile prefetch, counted vmcnt.
// ===========================================================================
template<int D>
__device__ __forceinline__ void ktile_body(
    unsigned short (&As)[2][2][8192], unsigned short (&Bs)[2][2][8192],
    const unsigned short* pA0, const unsigned short* pA1,
    const unsigned short* pB0, const unsigned short* pB1,
    size_t hK, int stoff, bool pf,
    int wm, int wn, int r16, int kg, int wave,
    f32x4 (&acc)[8][4], short8 (&af)[4][2], short8 (&b0f)[2][2], short8 (&b1f)[2][2])
{
    // ---- P1 ----
    #pragma unroll
    for (int mi = 0; mi < 4; ++mi)
        #pragma unroll
        for (int kk = 0; kk < 2; ++kk)
            af[mi][kk] = *(const short8*)&As[D][wm][AOFF(mi * 16 + r16, kk * 4 + kg)];
    #pragma unroll
    for (int ni = 0; ni < 2; ++ni)
        #pragma unroll
        for (int kk = 0; kk < 2; ++kk)
            b0f[ni][kk] = *(const short8*)&Bs[D][wn >> 1][AOFF((wn & 1) * 64 + ni * 16 + r16, kk * 4 + kg)];
    BARRIER();
    LGKM0();
    __builtin_amdgcn_s_setprio(1);
    #pragma unroll
    for (int mi = 0; mi < 4; ++mi)
        #pragma unroll
        for (int ni = 0; ni < 2; ++ni)
            #pragma unroll
            for (int kk = 0; kk < 2; ++kk)
                acc[mi][ni] = __builtin_amdgcn_mfma_f32_16x16x32_bf16(af[mi][kk], b0f[ni][kk], acc[mi][ni], 0, 0, 0);
    __builtin_amdgcn_s_setprio(0);
    BARRIER();

    // ---- P2 ----
    #pragma unroll
    for (int ni = 0; ni < 2; ++ni)
        #pragma unroll
        for (int kk = 0; kk < 2; ++kk)
            b1f[ni][kk] = *(const short8*)&Bs[D][wn >> 1][AOFF((wn & 1) * 64 + (ni + 2) * 16 + r16, kk * 4 + kg)];
    BARRIER();
    LGKM0();
    __builtin_amdgcn_s_setprio(1);
    #pragma unroll
    for (int mi = 0; mi < 4; ++mi)
        #pragma unroll
        for (int ni = 0; ni < 2; ++ni)
            #pragma unroll
            for (int kk = 0; kk < 2; ++kk)
                acc[mi][ni + 2] = __builtin_amdgcn_mfma_f32_16x16x32_bf16(af[mi][kk], b1f[ni][kk], acc[mi][ni + 2], 0, 0, 0);
    __builtin_amdgcn_s_setprio(0);
    BARRIER();

    // ---- P3; stage B(+2) ----
    #pragma unroll
    for (int mi = 0; mi < 4; ++mi)
        #pragma unroll
        for (int kk = 0; kk < 2; ++kk)
            af[mi][kk] = *(const short8*)&As[D][wm][AOFF((mi + 4) * 16 + r16, kk * 4 + kg)];
    if (pf) {
        gload16(pB0 + stoff,      &Bs[D][0][wave * 512]);
        gload16(pB1 + stoff,      &Bs[D][0][4096 + wave * 512]);
        gload16(pB0 + hK + stoff, &Bs[D][1][wave * 512]);
        gload16(pB1 + hK + stoff, &Bs[D][1][4096 + wave * 512]);
    }
    BARRIER();
    LGKM0();
    __builtin_amdgcn_s_setprio(1);
    #pragma unroll
    for (int mi = 0; mi < 4; ++mi)
        #pragma unroll
        for (int ni = 0; ni < 2; ++ni)
            #pragma unroll
            for (int kk = 0; kk < 2; ++kk)
                acc[mi + 4][ni + 2] = __builtin_amdgcn_mfma_f32_16x16x32_bf16(af[mi][kk], b1f[ni][kk], acc[mi + 4][ni + 2], 0, 0, 0);
    __builtin_amdgcn_s_setprio(0);
    BARRIER();

    // ---- P4; stage A(+2) ----
    if (pf) {
        gload16(pA0 + stoff,      &As[D][0][wave * 512]);
        gload16(pA1 + stoff,      &As[D][0][4096 + wave * 512]);
        gload16(pA0 + hK + stoff, &As[D][1][wave * 512]);
        gload16(pA1 + hK + stoff, &As[D][1][4096 + wave * 512]);
    }
    __builtin_amdgcn_s_setprio(1);
    #pragma unroll
    for (int mi = 0; mi < 4; ++mi)
        #pragma unroll
        for (int ni = 0; ni < 2; ++ni)
            #pragma unroll
            for (int kk = 0; kk < 2; ++kk)
                acc[mi + 4][ni] = __builtin_amdgcn_mfma_f32_16x16x32_bf16(af[mi][kk], b0f[ni][kk], acc[mi + 4][ni], 0, 0, 0);
    __builtin_amdgcn_s_setprio(0);
    if (pf) { VMCNT(8); }
    else    { VMCNT(0); }
    BARRIER();
}

__global__ __launch_bounds__(512, 2) void k_down(
    const unsigned short* __restrict__ A, const unsigned short* __restrict__ B,
    float* __restrict__ Cf, const int K, const int ldC)
{
    __shared__ unsigned short As[2][2][8192];
    __shared__ unsigned short Bs[2][2][8192];

    const int tid  = threadIdx.x;
    const int wave = tid >> 6;
    const int lane = tid & 63;
    const int wm   = wave >> 2;
    const int wn   = wave & 3;
    const int r16  = lane & 15;
    const int kg   = lane >> 4;

    const int nwg = gridDim.x;
    const int bid = blockIdx.x;
    const int swz = (bid & 7) * (nwg >> 3) + (bid >> 3);
    const int m0  = (swz & 31) * 256;
    const int n0  = (swz >> 5) * 256;

    const int i0 = tid,       r0 = i0 >> 3;
    const int i1 = 512 + tid, r1 = i1 >> 3;
    const int cc0 = (i0 & 7) ^ (r0 & 7);
    const int cc1 = (i1 & 7) ^ (r1 & 7);
    const size_t hK = (size_t)128 * K;

    const unsigned short* pA0 = A + (size_t)(m0 + r0) * K + cc0 * 8;
    const unsigned short* pA1 = A + (size_t)(m0 + r1) * K + cc1 * 8;
    const unsigned short* pB0 = B + (size_t)(n0 + r0) * K + cc0 * 8;
    const unsigned short* pB1 = B + (size_t)(n0 + r1) * K + cc1 * 8;

    f32x4 acc[8][4] = {};
    short8 af[4][2], b0f[2][2], b1f[2][2];

    const int NT = K >> 6;   // 172 (even)

    gload16(pA0,      &As[0][0][wave * 512]);
    gload16(pA1,      &As[0][0][4096 + wave * 512]);
    gload16(pA0 + hK, &As[0][1][wave * 512]);
    gload16(pA1 + hK, &As[0][1][4096 + wave * 512]);
    gload16(pB0,      &Bs[0][0][wave * 512]);
    gload16(pB1,      &Bs[0][0][4096 + wave * 512]);
    gload16(pB0 + hK, &Bs[0][1][wave * 512]);
    gload16(pB1 + hK, &Bs[0][1][4096 + wave * 512]);
    gload16(pA0 + 64,      &As[1][0][wave * 512]);
    gload16(pA1 + 64,      &As[1][0][4096 + wave * 512]);
    gload16(pA0 + hK + 64, &As[1][1][wave * 512]);
    gload16(pA1 + hK + 64, &As[1][1][4096 + wave * 512]);
    gload16(pB0 + 64,      &Bs[1][0][wave * 512]);
    gload16(pB1 + 64,      &Bs[1][0][4096 + wave * 512]);
    gload16(pB0 + hK + 64, &Bs[1][1][wave * 512]);
    gload16(pB1 + hK + 64, &Bs[1][1][4096 + wave * 512]);
    VMCNT(8);
    BARRIER();

    for (int kt = 0; kt < NT; kt += 2) {
        const bool pf0 = (kt + 2) < NT;
        const bool pf1 = (kt + 3) < NT;
        ktile_body<0>(As, Bs, pA0, pA1, pB0, pB1, hK, 128, pf0,
                      wm, wn, r16, kg, wave, acc, af, b0f, b1f);
        ktile_body<1>(As, Bs, pA0, pA1, pB0, pB1, hK, 192, pf1,
                      wm, wn, r16, kg, wave, acc, af, b0f, b1f);
        pA0 += 128; pA1 += 128; pB0 += 128; pB1 += 128;
    }

    #pragma unroll
    for (int mi = 0; mi < 8; ++mi)
        #pragma unroll
        for (int ni = 0; ni < 4; ++ni) {
            const int row = m0 + wm * 128 + mi * 16 + kg * 4;
            const int col = n0 + wn * 64 + ni * 16 + r16;
            f32x4 v = acc[mi][ni];
            #pragma unroll
            for (int rr = 0; rr < 4; ++rr)
                Cf[(size_t)(row + rr) * ldC + col] = v[rr];
        }
}

extern "C" void kernel_launch(void* const* d_in, const int* in_sizes, int n_in,
                              void* d_out, int out_size, void* d_ws, size_t ws_size,
                              hipStream_t stream) {
    const float* x  = (const float*)d_in[0];
    const float* wg = (const float*)d_in[1];
    const float* wu = (const float*)d_in[2];
    const float* wd = (const float*)d_in[3];
    float* out = (float*)d_out;

    // ws layout (total 494.0 MB):
    // [inter: Md*Id bf16][xb: Md*Hd][wgb: Id*Hd][wub: Id*Hd][wdb: Id*Hd]
    unsigned short* inter = (unsigned short*)d_ws;
    unsigned short* xb  = (unsigned short*)((char*)d_ws + (size_t)Md * Id * 2);
    unsigned short* wgb = xb  + (size_t)Md * Hd;
    unsigned short* wub = wgb + (size_t)Id * Hd;
    unsigned short* wdb = wub + (size_t)Id * Hd;

    k_cvt<<<dim3(2048), dim3(256), 0, stream>>>(x,  xb,  Md * Hd / 8);
    k_cvt<<<dim3(2048), dim3(256), 0, stream>>>(wg, wgb, Id * Hd / 8);
    k_cvt<<<dim3(2048), dim3(256), 0, stream>>>(wu, wub, Id * Hd / 8);
    k_cvt<<<dim3(2048), dim3(256), 0, stream>>>(wd, wdb, Id * Hd / 8);

    // fused up+gate: inter = silu(x.wg^T) * (x.wu^T)
    k_upgate<<<dim3((Md / 256) * (Id / 128)), dim3(512), 0, stream>>>(xb, wgb, wub, inter);
    // down: out = inter . wd^T
    k_down<<<dim3((Md / 256) * (Hd / 256)), dim3(512), 0, stream>>>(inter, wdb, out, Id, Hd);
}

// Round 7
// 2065.426 us; speedup vs baseline: 1.5073x; 1.0956x over previous
//
#include <hip/hip_runtime.h>
#include <hip/hip_bf16.h>
#include <stdint.h>

// B,S,H,I = 4,2048,4096,11008 ; M = B*S = 8192
static constexpr int Hd = 4096;
static constexpr int Id = 11008;
static constexpr int Md = 8192;

using short8 = __attribute__((ext_vector_type(8))) short;
using f32x4  = __attribute__((ext_vector_type(4))) float;

__device__ __forceinline__ unsigned short f2bf(float x) {
    union { float f; unsigned u; } v; v.f = x;
    unsigned r = v.u + 0x7FFF + ((v.u >> 16) & 1);   // RNE
    return (unsigned short)(r >> 16);
}

typedef const __attribute__((address_space(1))) unsigned int* as1_u32p;
typedef __attribute__((address_space(3))) unsigned int* as3_u32p;

__device__ __forceinline__ void gload16(const unsigned short* g, unsigned short* l) {
    __builtin_amdgcn_global_load_lds((as1_u32p)(const void*)g, (as3_u32p)(void*)l, 16, 0, 0);
}

// swizzled chunk offset (ushort index) within a [rows][64 cols] bf16 tile.
#define AOFF(r, c) ((((r) * 8) + ((c) ^ ((r) & 7))) * 8)

#define LGKM0() do { asm volatile("s_waitcnt lgkmcnt(0)" ::: "memory"); \
                     __builtin_amdgcn_sched_barrier(0); } while (0)
#define VMCNT(n) do { asm volatile("s_waitcnt vmcnt(" #n ")" ::: "memory"); \
                      __builtin_amdgcn_sched_barrier(0); } while (0)
#define BARRIER() do { asm volatile("" ::: "memory"); __builtin_amdgcn_s_barrier(); \
                       asm volatile("" ::: "memory"); } while (0)

// ---------------------------------------------------------------------------
// fp32 -> bf16 bulk converter
// ---------------------------------------------------------------------------
__global__ __launch_bounds__(256) void k_cvt(const float* __restrict__ in,
                                             unsigned short* __restrict__ out, int n8) {
    int i = blockIdx.x * blockDim.x + threadIdx.x;
    const int stride = gridDim.x * blockDim.x;
    for (; i < n8; i += stride) {
        f32x4 a = *(const f32x4*)(in + (size_t)i * 8);
        f32x4 b = *(const f32x4*)(in + (size_t)i * 8 + 4);
        short8 v;
        v[0] = (short)f2bf(a[0]); v[1] = (short)f2bf(a[1]);
        v[2] = (short)f2bf(a[2]); v[3] = (short)f2bf(a[3]);
        v[4] = (short)f2bf(b[0]); v[5] = (short)f2bf(b[1]);
        v[6] = (short)f2bf(b[2]); v[7] = (short)f2bf(b[3]);
        *reinterpret_cast<short8*>(out + (size_t)i * 8) = v;
    }
}

// ===========================================================================
// FUSED up+gate kernel: inter[m,i] = silu(x.wg^T)[m,i] * (x.wu^T)[m,i]
// Block tile 256(m) x 128(i), BK=64, 8 waves (2m x 4n), wave tile 128x32 per
// matrix, dual accumulators, 4-phase pipelined, 2-tile-deep prefetch,
// counted vmcnt. K = Hd = 4096 (compile-time).
// ===========================================================================
template<int D>
__device__ __forceinline__ void ug_body(
    unsigned short (&As)[2][2][8192], unsigned short (&Gs)[2][8192], unsigned short (&Us)[2][8192],
    const unsigned short* pA0, const unsigned short* pA1,
    const unsigned short* pG0, const unsigned short* pG1,
    const unsigned short* pU0, const unsigned short* pU1,
    int stoff, bool pf,
    int wm, int wn, int r16, int kg, int wave,
    f32x4 (&accg)[8][2], f32x4 (&accu)[8][2])
{
    constexpr size_t hK = (size_t)128 * Hd;
    short8 af[4][2], gf[2][2], uf[2][2];

    // ---- P1: G quadrant mi 0-3 ----
    #pragma unroll
    for (int mi = 0; mi < 4; ++mi)
        #pragma unroll
        for (int kk = 0; kk < 2; ++kk)
            af[mi][kk] = *(const short8*)&As[D][wm][AOFF(mi * 16 + r16, kk * 4 + kg)];
    #pragma unroll
    for (int ni = 0; ni < 2; ++ni)
        #pragma unroll
        for (int kk = 0; kk < 2; ++kk)
            gf[ni][kk] = *(const short8*)&Gs[D][AOFF(wn * 32 + ni * 16 + r16, kk * 4 + kg)];
    BARRIER();
    LGKM0();
    __builtin_amdgcn_s_setprio(1);
    #pragma unroll
    for (int mi = 0; mi < 4; ++mi)
        #pragma unroll
        for (int ni = 0; ni < 2; ++ni)
            #pragma unroll
            for (int kk = 0; kk < 2; ++kk)
                accg[mi][ni] = __builtin_amdgcn_mfma_f32_16x16x32_bf16(af[mi][kk], gf[ni][kk], accg[mi][ni], 0, 0, 0);
    __builtin_amdgcn_s_setprio(0);
    BARRIER();

    // ---- P2: U quadrant mi 0-3 (af reuse); stage G(kt+2) ----
    #pragma unroll
    for (int ni = 0; ni < 2; ++ni)
        #pragma unroll
        for (int kk = 0; kk < 2; ++kk)
            uf[ni][kk] = *(const short8*)&Us[D][AOFF(wn * 32 + ni * 16 + r16, kk * 4 + kg)];
    if (pf) {
        gload16(pG0 + stoff, &Gs[D][wave * 512]);
        gload16(pG1 + stoff, &Gs[D][4096 + wave * 512]);
    }
    BARRIER();
    LGKM0();
    __builtin_amdgcn_s_setprio(1);
    #pragma unroll
    for (int mi = 0; mi < 4; ++mi)
        #pragma unroll
        for (int ni = 0; ni < 2; ++ni)
            #pragma unroll
            for (int kk = 0; kk < 2; ++kk)
                accu[mi][ni] = __builtin_amdgcn_mfma_f32_16x16x32_bf16(af[mi][kk], uf[ni][kk], accu[mi][ni], 0, 0, 0);
    __builtin_amdgcn_s_setprio(0);
    BARRIER();

    // ---- P3: G quadrant mi 4-7 (gf reuse); stage U(kt+2) ----
    #pragma unroll
    for (int mi = 0; mi < 4; ++mi)
        #pragma unroll
        for (int kk = 0; kk < 2; ++kk)
            af[mi][kk] = *(const short8*)&As[D][wm][AOFF((mi + 4) * 16 + r16, kk * 4 + kg)];
    if (pf) {
        gload16(pU0 + stoff, &Us[D][wave * 512]);
        gload16(pU1 + stoff, &Us[D][4096 + wave * 512]);
    }
    BARRIER();
    LGKM0();
    __builtin_amdgcn_s_setprio(1);
    #pragma unroll
    for (int mi = 0; mi < 4; ++mi)
        #pragma unroll
        for (int ni = 0; ni < 2; ++ni)
            #pragma unroll
            for (int kk = 0; kk < 2; ++kk)
                accg[mi + 4][ni] = __builtin_amdgcn_mfma_f32_16x16x32_bf16(af[mi][kk], gf[ni][kk], accg[mi + 4][ni], 0, 0, 0);
    __builtin_amdgcn_s_setprio(0);
    BARRIER();

    // ---- P4: U quadrant mi 4-7 (af+uf reuse); stage A(kt+2) ----
    if (pf) {
        gload16(pA0 + stoff,      &As[D][0][wave * 512]);
        gload16(pA1 + stoff,      &As[D][0][4096 + wave * 512]);
        gload16(pA0 + hK + stoff, &As[D][1][wave * 512]);
        gload16(pA1 + hK + stoff, &As[D][1][4096 + wave * 512]);
    }
    __builtin_amdgcn_s_setprio(1);
    #pragma unroll
    for (int mi = 0; mi < 4; ++mi)
        #pragma unroll
        for (int ni = 0; ni < 2; ++ni)
            #pragma unroll
            for (int kk = 0; kk < 2; ++kk)
                accu[mi + 4][ni] = __builtin_amdgcn_mfma_f32_16x16x32_bf16(af[mi][kk], uf[ni][kk], accu[mi + 4][ni], 0, 0, 0);
    __builtin_amdgcn_s_setprio(0);
    if (pf) { VMCNT(8); }   // tile (this+1) landed; (this+2) stays in flight
    else    { VMCNT(0); }
    BARRIER();
}

__global__ __launch_bounds__(512, 2) void k_upgate(
    const unsigned short* __restrict__ A,   // xb  [Md][Hd]
    const unsigned short* __restrict__ G,   // wgb [Id][Hd]
    const unsigned short* __restrict__ U,   // wub [Id][Hd]
    unsigned short* __restrict__ inter)     // [Md][Id]
{
    __shared__ unsigned short As[2][2][8192];  // 64 KiB: [dbuf][half][128*64]
    __shared__ unsigned short Gs[2][8192];     // 32 KiB: [dbuf][128*64]
    __shared__ unsigned short Us[2][8192];     // 32 KiB

    const int tid  = threadIdx.x;
    const int wave = tid >> 6;
    const int lane = tid & 63;
    const int wm   = wave >> 2;          // 0..1 -> rows wm*128
    const int wn   = wave & 3;           // 0..3 -> cols wn*32
    const int r16  = lane & 15;
    const int kg   = lane >> 4;

    // rasterization: XCD-contiguous chunks; within: GROUP_M=8 m-tiles,
    // m fastest inside the group (weight-panel L2 reuse), n-major across
    // (the group's 8 A-panels stay L3-resident for the whole n sweep).
    const int nwg = gridDim.x;           // 2752 = 32m x 86n, %8==0
    const int bid = blockIdx.x;
    const int swz = (bid & 7) * (nwg >> 3) + (bid >> 3);   // XCD swizzle
    const int grp = swz / 688;           // 688 = 8 * 86 blocks per m-group
    const int rem = swz % 688;
    const int m0  = (grp * 8 + (rem & 7)) * 256;
    const int n0  = (rem >> 3) * 128;

    const int i0 = tid,       r0 = i0 >> 3;
    const int i1 = 512 + tid, r1 = i1 >> 3;
    const int cc0 = (i0 & 7) ^ (r0 & 7);
    const int cc1 = (i1 & 7) ^ (r1 & 7);
    constexpr size_t hK = (size_t)128 * Hd;

    const unsigned short* pA0 = A + (size_t)(m0 + r0) * Hd + cc0 * 8;
    const unsigned short* pA1 = A + (size_t)(m0 + r1) * Hd + cc1 * 8;
    const unsigned short* pG0 = G + (size_t)(n0 + r0) * Hd + cc0 * 8;
    const unsigned short* pG1 = G + (size_t)(n0 + r1) * Hd + cc1 * 8;
    const unsigned short* pU0 = U + (size_t)(n0 + r0) * Hd + cc0 * 8;
    const unsigned short* pU1 = U + (size_t)(n0 + r1) * Hd + cc1 * 8;

    f32x4 accg[8][2] = {};
    f32x4 accu[8][2] = {};

    constexpr int NT = Hd >> 6;   // 64 (even)

    // prologue: tile 0 -> bufs[0], tile 1 -> bufs[1] (8 loads/thread each)
    gload16(pA0,      &As[0][0][wave * 512]);
    gload16(pA1,      &As[0][0][4096 + wave * 512]);
    gload16(pA0 + hK, &As[0][1][wave * 512]);
    gload16(pA1 + hK, &As[0][1][4096 + wave * 512]);
    gload16(pG0,      &Gs[0][wave * 512]);
    gload16(pG1,      &Gs[0][4096 + wave * 512]);
    gload16(pU0,      &Us[0][wave * 512]);
    gload16(pU1,      &Us[0][4096 + wave * 512]);
    gload16(pA0 + 64,      &As[1][0][wave * 512]);
    gload16(pA1 + 64,      &As[1][0][4096 + wave * 512]);
    gload16(pA0 + hK + 64, &As[1][1][wave * 512]);
    gload16(pA1 + hK + 64, &As[1][1][4096 + wave * 512]);
    gload16(pG0 + 64,      &Gs[1][wave * 512]);
    gload16(pG1 + 64,      &Gs[1][4096 + wave * 512]);
    gload16(pU0 + 64,      &Us[1][wave * 512]);
    gload16(pU1 + 64,      &Us[1][4096 + wave * 512]);
    VMCNT(8);
    BARRIER();

    for (int kt = 0; kt < NT; kt += 2) {
        const bool pf0 = (kt + 2) < NT;
        const bool pf1 = (kt + 3) < NT;
        ug_body<0>(As, Gs, Us, pA0, pA1, pG0, pG1, pU0, pU1, 128, pf0,
                   wm, wn, r16, kg, wave, accg, accu);
        ug_body<1>(As, Gs, Us, pA0, pA1, pG0, pG1, pU0, pU1, 192, pf1,
                   wm, wn, r16, kg, wave, accg, accu);
        pA0 += 128; pA1 += 128; pG0 += 128; pG1 += 128; pU0 += 128; pU1 += 128;
    }

    // epilogue: in-register SwiGLU, single write of inter
    #pragma unroll
    for (int mi = 0; mi < 8; ++mi)
        #pragma unroll
        for (int ni = 0; ni < 2; ++ni) {
            const int row = m0 + wm * 128 + mi * 16 + kg * 4;
            const int col = n0 + wn * 32 + ni * 16 + r16;
            f32x4 g = accg[mi][ni], u = accu[mi][ni];
            #pragma unroll
            for (int rr = 0; rr < 4; ++rr) {
                float gv = g[rr];
                float s  = gv / (1.0f + __expf(-gv));
                inter[(size_t)(row + rr) * Id + col] = f2bf(s * u[rr]);
            }
        }
}

// ===========================================================================
// Down GEMM: out = inter . wd^T, fp32 out
// 256x256 tile, BK=64, 8 waves, 4-phase, 2-tile prefetch, counted vmcnt.
// ===========================================================================
template<int D>
__device__ __forceinline__ void ktile_body(
    unsigned short (&As)[2][2][8192], unsigned short (&Bs)[2][2][8192],
    const unsigned short* pA0, const unsigned short* pA1,
    const unsigned short* pB0, const unsigned short* pB1,
    size_t hK, int stoff, bool pf,
    int wm, int wn, int r16, int kg, int wave,
    f32x4 (&acc)[8][4], short8 (&af)[4][2], short8 (&b0f)[2][2], short8 (&b1f)[2][2])
{
    // ---- P1 ----
    #pragma unroll
    for (int mi = 0; mi < 4; ++mi)
        #pragma unroll
        for (int kk = 0; kk < 2; ++kk)
            af[mi][kk] = *(const short8*)&As[D][wm][AOFF(mi * 16 + r16, kk * 4 + kg)];
    #pragma unroll
    for (int ni = 0; ni < 2; ++ni)
        #pragma unroll
        for (int kk = 0; kk < 2; ++kk)
            b0f[ni][kk] = *(const short8*)&Bs[D][wn >> 1][AOFF((wn & 1) * 64 + ni * 16 + r16, kk * 4 + kg)];
    BARRIER();
    LGKM0();
    __builtin_amdgcn_s_setprio(1);
    #pragma unroll
    for (int mi = 0; mi < 4; ++mi)
        #pragma unroll
        for (int ni = 0; ni < 2; ++ni)
            #pragma unroll
            for (int kk = 0; kk < 2; ++kk)
                acc[mi][ni] = __builtin_amdgcn_mfma_f32_16x16x32_bf16(af[mi][kk], b0f[ni][kk], acc[mi][ni], 0, 0, 0);
    __builtin_amdgcn_s_setprio(0);
    BARRIER();

    // ---- P2 ----
    #pragma unroll
    for (int ni = 0; ni < 2; ++ni)
        #pragma unroll
        for (int kk = 0; kk < 2; ++kk)
            b1f[ni][kk] = *(const short8*)&Bs[D][wn >> 1][AOFF((wn & 1) * 64 + (ni + 2) * 16 + r16, kk * 4 + kg)];
    BARRIER();
    LGKM0();
    __builtin_amdgcn_s_setprio(1);
    #pragma unroll
    for (int mi = 0; mi < 4; ++mi)
        #pragma unroll
        for (int ni = 0; ni < 2; ++ni)
            #pragma unroll
            for (int kk = 0; kk < 2; ++kk)
                acc[mi][ni + 2] = __builtin_amdgcn_mfma_f32_16x16x32_bf16(af[mi][kk], b1f[ni][kk], acc[mi][ni + 2], 0, 0, 0);
    __builtin_amdgcn_s_setprio(0);
    BARRIER();

    // ---- P3; stage B(+2) ----
    #pragma unroll
    for (int mi = 0; mi < 4; ++mi)
        #pragma unroll
        for (int kk = 0; kk < 2; ++kk)
            af[mi][kk] = *(const short8*)&As[D][wm][AOFF((mi + 4) * 16 + r16, kk * 4 + kg)];
    if (pf) {
        gload16(pB0 + stoff,      &Bs[D][0][wave * 512]);
        gload16(pB1 + stoff,      &Bs[D][0][4096 + wave * 512]);
        gload16(pB0 + hK + stoff, &Bs[D][1][wave * 512]);
        gload16(pB1 + hK + stoff, &Bs[D][1][4096 + wave * 512]);
    }
    BARRIER();
    LGKM0();
    __builtin_amdgcn_s_setprio(1);
    #pragma unroll
    for (int mi = 0; mi < 4; ++mi)
        #pragma unroll
        for (int ni = 0; ni < 2; ++ni)
            #pragma unroll
            for (int kk = 0; kk < 2; ++kk)
                acc[mi + 4][ni + 2] = __builtin_amdgcn_mfma_f32_16x16x32_bf16(af[mi][kk], b1f[ni][kk], acc[mi + 4][ni + 2], 0, 0, 0);
    __builtin_amdgcn_s_setprio(0);
    BARRIER();

    // ---- P4; stage A(+2) ----
    if (pf) {
        gload16(pA0 + stoff,      &As[D][0][wave * 512]);
        gload16(pA1 + stoff,      &As[D][0][4096 + wave * 512]);
        gload16(pA0 + hK + stoff, &As[D][1][wave * 512]);
        gload16(pA1 + hK + stoff, &As[D][1][4096 + wave * 512]);
    }
    __builtin_amdgcn_s_setprio(1);
    #pragma unroll
    for (int mi = 0; mi < 4; ++mi)
        #pragma unroll
        for (int ni = 0; ni < 2; ++ni)
            #pragma unroll
            for (int kk = 0; kk < 2; ++kk)
                acc[mi + 4][ni] = __builtin_amdgcn_mfma_f32_16x16x32_bf16(af[mi][kk], b0f[ni][kk], acc[mi + 4][ni], 0, 0, 0);
    __builtin_amdgcn_s_setprio(0);
    if (pf) { VMCNT(8); }
    else    { VMCNT(0); }
    BARRIER();
}

__global__ __launch_bounds__(512, 2) void k_down(
    const unsigned short* __restrict__ A, const unsigned short* __restrict__ B,
    float* __restrict__ Cf, const int K, const int ldC)
{
    __shared__ unsigned short As[2][2][8192];
    __shared__ unsigned short Bs[2][2][8192];

    const int tid  = threadIdx.x;
    const int wave = tid >> 6;
    const int lane = tid & 63;
    const int wm   = wave >> 2;
    const int wn   = wave & 3;
    const int r16  = lane & 15;
    const int kg   = lane >> 4;

    // rasterization: XCD chunks; GROUP_M=8 m-tiles, m fastest, n-major.
    const int nwg = gridDim.x;           // 512 = 32m x 16n
    const int bid = blockIdx.x;
    const int swz = (bid & 7) * (nwg >> 3) + (bid >> 3);
    const int grp = swz / 128;           // 128 = 8 * 16 blocks per m-group
    const int rem = swz % 128;
    const int m0  = (grp * 8 + (rem & 7)) * 256;
    const int n0  = (rem >> 3) * 256;

    const int i0 = tid,       r0 = i0 >> 3;
    const int i1 = 512 + tid, r1 = i1 >> 3;
    const int cc0 = (i0 & 7) ^ (r0 & 7);
    const int cc1 = (i1 & 7) ^ (r1 & 7);
    const size_t hK = (size_t)128 * K;

    const unsigned short* pA0 = A + (size_t)(m0 + r0) * K + cc0 * 8;
    const unsigned short* pA1 = A + (size_t)(m0 + r1) * K + cc1 * 8;
    const unsigned short* pB0 = B + (size_t)(n0 + r0) * K + cc0 * 8;
    const unsigned short* pB1 = B + (size_t)(n0 + r1) * K + cc1 * 8;

    f32x4 acc[8][4] = {};
    short8 af[4][2], b0f[2][2], b1f[2][2];

    const int NT = K >> 6;   // 172 (even)

    gload16(pA0,      &As[0][0][wave * 512]);
    gload16(pA1,      &As[0][0][4096 + wave * 512]);
    gload16(pA0 + hK, &As[0][1][wave * 512]);
    gload16(pA1 + hK, &As[0][1][4096 + wave * 512]);
    gload16(pB0,      &Bs[0][0][wave * 512]);
    gload16(pB1,      &Bs[0][0][4096 + wave * 512]);
    gload16(pB0 + hK, &Bs[0][1][wave * 512]);
    gload16(pB1 + hK, &Bs[0][1][4096 + wave * 512]);
    gload16(pA0 + 64,      &As[1][0][wave * 512]);
    gload16(pA1 + 64,      &As[1][0][4096 + wave * 512]);
    gload16(pA0 + hK + 64, &As[1][1][wave * 512]);
    gload16(pA1 + hK + 64, &As[1][1][4096 + wave * 512]);
    gload16(pB0 + 64,      &Bs[1][0][wave * 512]);
    gload16(pB1 + 64,      &Bs[1][0][4096 + wave * 512]);
    gload16(pB0 + hK + 64, &Bs[1][1][wave * 512]);
    gload16(pB1 + hK + 64, &Bs[1][1][4096 + wave * 512]);
    VMCNT(8);
    BARRIER();

    for (int kt = 0; kt < NT; kt += 2) {
        const bool pf0 = (kt + 2) < NT;
        const bool pf1 = (kt + 3) < NT;
        ktile_body<0>(As, Bs, pA0, pA1, pB0, pB1, hK, 128, pf0,
                      wm, wn, r16, kg, wave, acc, af, b0f, b1f);
        ktile_body<1>(As, Bs, pA0, pA1, pB0, pB1, hK, 192, pf1,
                      wm, wn, r16, kg, wave, acc, af, b0f, b1f);
        pA0 += 128; pA1 += 128; pB0 += 128; pB1 += 128;
    }

    #pragma unroll
    for (int mi = 0; mi < 8; ++mi)
        #pragma unroll
        for (int ni = 0; ni < 4; ++ni) {
            const int row = m0 + wm * 128 + mi * 16 + kg * 4;
            const int col = n0 + wn * 64 + ni * 16 + r16;
            f32x4 v = acc[mi][ni];
            #pragma unroll
            for (int rr = 0; rr < 4; ++rr)
                Cf[(size_t)(row + rr) * ldC + col] = v[rr];
        }
}

extern "C" void kernel_launch(void* const* d_in, const int* in_sizes, int n_in,
                              void* d_out, int out_size, void* d_ws, size_t ws_size,
                              hipStream_t stream) {
    const float* x  = (const float*)d_in[0];
    const float* wg = (const float*)d_in[1];
    const float* wu = (const float*)d_in[2];
    const float* wd = (const float*)d_in[3];
    float* out = (float*)d_out;

    // ws layout (total 494.0 MB):
    // [inter: Md*Id bf16][xb: Md*Hd][wgb: Id*Hd][wub: Id*Hd][wdb: Id*Hd]
    unsigned short* inter = (unsigned short*)d_ws;
    unsigned short* xb  = (unsigned short*)((char*)d_ws + (size_t)Md * Id * 2);
    unsigned short* wgb = xb  + (size_t)Md * Hd;
    unsigned short* wub = wgb + (size_t)Id * Hd;
    unsigned short* wdb = wub + (size_t)Id * Hd;

    k_cvt<<<dim3(2048), dim3(256), 0, stream>>>(x,  xb,  Md * Hd / 8);
    k_cvt<<<dim3(2048), dim3(256), 0, stream>>>(wg, wgb, Id * Hd / 8);
    k_cvt<<<dim3(2048), dim3(256), 0, stream>>>(wu, wub, Id * Hd / 8);
    k_cvt<<<dim3(2048), dim3(256), 0, stream>>>(wd, wdb, Id * Hd / 8);

    // fused up+gate: inter = silu(x.wg^T) * (x.wu^T)
    k_upgate<<<dim3((Md / 256) * (Id / 128)), dim3(512), 0, stream>>>(xb, wgb, wub, inter);
    // down: out = inter . wd^T
    k_down<<<dim3((Md / 256) * (Hd / 256)), dim3(512), 0, stream>>>(inter, wdb, out, Id, Hd);
}